// Round 4
// baseline (527.777 us; speedup 1.0000x reference)
//
#include <hip/hip_runtime.h>

#define B 8
#define K 16
#define H 224
#define W 224
#define PH 232
#define PW 232
#define WIN 9
#define WQ 56                 // W / 4 pixels per quad-row
#define NQUAD (B * H * WQ)    // 100352 quads
#define BLK 256
#define NWAVE ((NQUAD / 64) * 2)   // 3136 waves (m-split x2)
#define NB (NWAVE / 4)             // 784 blocks
#define NBX (NB / 8)               // 98 blocks per XCD = exactly one batch image b

// 4-float vector with only 4B alignment guarantee (weight rows are 4B-aligned)
typedef float vf4 __attribute__((ext_vector_type(4), aligned(4)));
typedef float vf4a __attribute__((ext_vector_type(4)));  // 16B-aligned

__global__ __launch_bounds__(BLK, 3) void ncuts_main(
    const float* __restrict__ seg,      // [B][K][H][W]
    const float* __restrict__ padded,   // [B][K][PH][PW]
    const float* __restrict__ weight,   // [B][H][W][9][9]
    const float* __restrict__ sumw,     // [B][H][W]
    float* __restrict__ ws)             // ws[0..127]=A[b][k], ws[128..255]=V[b][k]
{
    const int lane = threadIdx.x & 63;
    const int widx = threadIdx.x >> 6;
    // XCD-locality swizzle: block i -> XCD i%8; remap so XCD x owns batch b=x.
    const int bsw = (blockIdx.x & 7) * NBX + (blockIdx.x >> 3);
    const int gw  = bsw * 4 + widx;     // global wave id
    const int mh  = gw & 1;             // m-half: 0 -> m in [0,5), 1 -> [5,9)
    const int qw  = gw >> 1;            // quad-wave id, 0..1567
    const int q   = qw * 64 + lane;     // quad id, 0..100351
    const int wq  = q % WQ;
    const int t   = q / WQ;
    const int h   = t % H;
    const int b   = t / H;
    const int w0  = wq * 4;
    const int m_lo = mh ? 5 : 0;
    const int m_hi = mh ? 9 : 5;

    float acc[K][4];
#pragma unroll
    for (int k = 0; k < K; ++k)
#pragma unroll
        for (int p = 0; p < 4; ++p) acc[k][p] = 0.f;

    const long pixbase = ((long)(b * H + h)) * W + w0;
    const float* wbase = weight + pixbase * 81;
    const float* pbase = padded + ((long)(b * K) * PH + h) * PW + w0;

#pragma unroll 1
    for (int m = m_lo; m < m_hi; ++m) {
        // weight: zero cross-thread reuse -> nontemporal, keeps L2 for padded
        float wr[4][WIN];
#pragma unroll
        for (int p = 0; p < 4; ++p) {
            const float* wp = wbase + (long)p * 81 + m * 9;
            vf4 wa = __builtin_nontemporal_load((const vf4*)wp);
            vf4 wb = __builtin_nontemporal_load((const vf4*)(wp + 4));
            float wc = __builtin_nontemporal_load(wp + 8);
            wr[p][0] = wa.x; wr[p][1] = wa.y; wr[p][2] = wa.z; wr[p][3] = wa.w;
            wr[p][4] = wb.x; wr[p][5] = wb.y; wr[p][6] = wb.z; wr[p][7] = wb.w;
            wr[p][8] = wc;
        }
        const float* prow = pbase + (long)m * PW;

        // double-buffered 2-k batches: batch kb+1 is in flight while FMAs
        // consume batch kb -> compiler can overlap VMEM latency with VALU.
        float4 bufA[6], bufB[6];
        {
            const float4* r0 = (const float4*)(prow);
            const float4* r1 = (const float4*)(prow + (long)PH * PW);
            bufA[0] = r0[0]; bufA[1] = r0[1]; bufA[2] = r0[2];
            bufA[3] = r1[0]; bufA[4] = r1[1]; bufA[5] = r1[2];
        }
#pragma unroll
        for (int kb = 0; kb < 8; ++kb) {
            float4* cur = (kb & 1) ? bufB : bufA;
            float4* nxt = (kb & 1) ? bufA : bufB;
            if (kb < 7) {
                const float4* r0 = (const float4*)(prow + (long)(2 * kb + 2) * PH * PW);
                const float4* r1 = (const float4*)(prow + (long)(2 * kb + 3) * PH * PW);
                nxt[0] = r0[0]; nxt[1] = r0[1]; nxt[2] = r0[2];
                nxt[3] = r1[0]; nxt[4] = r1[1]; nxt[5] = r1[2];
            }
#pragma unroll
            for (int j = 0; j < 2; ++j) {
                const int k = 2 * kb + j;
                const float4 a0 = cur[3 * j], a1 = cur[3 * j + 1], a2 = cur[3 * j + 2];
                float win[12] = {a0.x, a0.y, a0.z, a0.w,
                                 a1.x, a1.y, a1.z, a1.w,
                                 a2.x, a2.y, a2.z, a2.w};
#pragma unroll
                for (int p = 0; p < 4; ++p)
#pragma unroll
                    for (int n = 0; n < WIN; ++n)
                        acc[k][p] = fmaf(win[p + n], wr[p][n], acc[k][p]);
            }
        }
    }

    // epilogue: partial assocA (both m-halves), assocV (mh==0 only, else double-counted)
    const vf4a sw4 = __builtin_nontemporal_load((const vf4a*)(sumw + pixbase));
    const float swv[4] = {sw4.x, sw4.y, sw4.z, sw4.w};
    const float* sbase = seg + ((long)(b * K) * H + h) * W + w0;

    float accA[K], accV[K];
#pragma unroll
    for (int k = 0; k < K; ++k) {
        const vf4a s4 = __builtin_nontemporal_load((const vf4a*)(sbase + (long)k * H * W));
        const float sv[4] = {s4.x, s4.y, s4.z, s4.w};
        float a = 0.f, v = 0.f;
#pragma unroll
        for (int p = 0; p < 4; ++p) {
            a = fmaf(acc[k][p], sv[p], a);
            v = fmaf(swv[p], sv[p], v);
        }
        accA[k] = a;
        accV[k] = v;
    }

#pragma unroll
    for (int k = 0; k < K; ++k) {
        float a = accA[k], v = accV[k];
#pragma unroll
        for (int off = 32; off > 0; off >>= 1) {
            a += __shfl_xor(a, off);
            v += __shfl_xor(v, off);
        }
        if (lane == 0) {
            atomicAdd(&ws[b * K + k], a);
            if (mh == 0) atomicAdd(&ws[128 + b * K + k], v);
        }
    }
}

__global__ void ncuts_final(const float* __restrict__ ws,
                            const int* __restrict__ ncut_k,
                            float* __restrict__ out)
{
    const int t = threadIdx.x;        // 128 threads: t = b*16 + k
    const int b = t >> 4;
    const int k = t & 15;
    float r = ws[b * K + k] / ws[128 + b * K + k];
#pragma unroll
    for (int off = 1; off < 16; off <<= 1) r += __shfl_xor(r, off, 16);
    if (k == 0) out[b] = (float)(*ncut_k) - r;
}

extern "C" void kernel_launch(void* const* d_in, const int* in_sizes, int n_in,
                              void* d_out, int out_size, void* d_ws, size_t ws_size,
                              hipStream_t stream) {
    (void)in_sizes; (void)n_in; (void)out_size; (void)ws_size;
    const float* seg    = (const float*)d_in[0];
    const float* padded = (const float*)d_in[1];
    const float* weight = (const float*)d_in[2];
    const float* sumw   = (const float*)d_in[3];
    const int*   nk     = (const int*)d_in[5];
    float* ws  = (float*)d_ws;
    float* out = (float*)d_out;

    hipMemsetAsync(ws, 0, 2 * B * K * sizeof(float), stream);
    ncuts_main<<<NB, BLK, 0, stream>>>(seg, padded, weight, sumw, ws);
    ncuts_final<<<1, 128, 0, stream>>>(ws, nk, out);
}

// Round 5
// 351.101 us; speedup vs baseline: 1.5032x; 1.5032x over previous
//
#include <hip/hip_runtime.h>

#define B 8
#define K 16
#define H 224
#define W 224
#define PH 232
#define PW 232
#define WIN 9

#define HT 16                 // output rows per tile
#define WT 32                 // output pixels per tile
#define KT 4                  // k-slices per block
#define ROWS (HT + 8)         // 24 staged padded rows
#define LDSW 64               // LDS row stride in floats (40 used + pad)
#define NHT (H / HT)          // 14
#define NWT (W / WT)          // 7
#define NKQ (K / KT)          // 4
#define NB (B * NHT * NWT * NKQ)   // 3136 blocks

typedef float vf4 __attribute__((ext_vector_type(4), aligned(4)));
typedef float vf4a __attribute__((ext_vector_type(4)));
typedef const __attribute__((address_space(1))) char gchar;
typedef __attribute__((address_space(3))) char lchar;

__global__ __launch_bounds__(128, 3) void ncuts_main(
    const float* __restrict__ seg,      // [B][K][H][W]
    const float* __restrict__ padded,   // [B][K][PH][PW]
    const float* __restrict__ weight,   // [B][H][W][9][9]
    const float* __restrict__ sumw,     // [B][H][W]
    float* __restrict__ ws)             // ws[0..127]=A[b][k], ws[128..255]=V[b][k]
{
    // 24 KB LDS: padded tile, 4 k-slices x 24 rows x 40 used floats (stride 64)
    __shared__ float lds[KT][ROWS][LDSW];

    const int tid  = threadIdx.x;
    const int lane = tid & 63;
    const int wv   = tid >> 6;          // wave 0/1

    // swizzle: XCD x (block i -> XCD i%8) owns batch b=x; a tile's 4 k-quarters
    // are consecutive in s -> dispatched ~simultaneously on the same XCD so the
    // weight tile is fetched from HBM once and served 3x from that XCD's L2.
    const int b    = blockIdx.x & 7;
    const int s    = blockIdx.x >> 3;   // 0..391
    const int kq   = s & 3;
    const int tile = s >> 2;            // 0..97
    const int ht   = tile / NWT;
    const int wt   = tile - ht * NWT;
    const int k0   = kq * KT;
    const int h0   = ht * HT;
    const int w0   = wt * WT;

    // ---- stage padded tile -> LDS via async DMA (no VGPR round-trip).
    // One instr covers 4 rows: lane = (row-in-batch<<4) | chunk; LDS dest is
    // base + lane*16 (wave-uniform base), so row stride must be 64 floats.
    // Chunks 10..15 clamp to chunk 9 (fill LDS pad, stay in-bounds).
    {
        const int rb = lane >> 4;
        const int c  = lane & 15;
        const int cc = c < 10 ? c : 9;
#pragma unroll
        for (int i = 0; i < 12; ++i) {
            const int j     = wv * 12 + i;     // 0..23
            const int kk    = j / 6;
            const int batch = j - kk * 6;      // 0..5 (4 rows each)
            const float* g = padded +
                (((long)(b * K + k0 + kk) * PH + (h0 + batch * 4 + rb)) * PW
                 + (w0 + 4 * cc));
            void* l = (void*)&lds[kk][batch * 4][0];
            __builtin_amdgcn_global_load_lds((gchar*)g, (lchar*)l, 16, 0, 0);
        }
    }
    __syncthreads();

    // ---- compute: thread = (row r, quad q) -> 4 pixels x 4 k's
    const int r  = tid >> 3;            // 0..15
    const int q  = tid & 7;             // 0..7
    const int h  = h0 + r;
    const int wp = w0 + 4 * q;
    const long pix = (long)(b * H + h) * W + wp;
    const float* wbase = weight + pix * 81;

    float acc[KT][4];
#pragma unroll
    for (int kk = 0; kk < KT; ++kk)
#pragma unroll
        for (int p = 0; p < 4; ++p) acc[kk][p] = 0.f;

#pragma unroll 1
    for (int m = 0; m < WIN; ++m) {
        // weight: plain cached loads — L1 holds the 64B-line straddle between
        // consecutive m (reuse distance ~450 cyc, ~11 KB/CU << 32 KB L1).
        float wr[4][WIN];
#pragma unroll
        for (int p = 0; p < 4; ++p) {
            const float* wpt = wbase + (long)p * 81 + m * 9;
            vf4 wa = *(const vf4*)wpt;
            vf4 wb = *(const vf4*)(wpt + 4);
            float wc = wpt[8];
            wr[p][0] = wa.x; wr[p][1] = wa.y; wr[p][2] = wa.z; wr[p][3] = wa.w;
            wr[p][4] = wb.x; wr[p][5] = wb.y; wr[p][6] = wb.z; wr[p][7] = wb.w;
            wr[p][8] = wc;
        }
#pragma unroll
        for (int kk = 0; kk < KT; ++kk) {
            const float4* pr = (const float4*)&lds[kk][r + m][4 * q]; // 16B aligned
            float4 a0 = pr[0], a1 = pr[1], a2 = pr[2];
            float win[12] = {a0.x, a0.y, a0.z, a0.w,
                             a1.x, a1.y, a1.z, a1.w,
                             a2.x, a2.y, a2.z, a2.w};
#pragma unroll
            for (int p = 0; p < 4; ++p)
#pragma unroll
                for (int n = 0; n < WIN; ++n)
                    acc[kk][p] = fmaf(win[p + n], wr[p][n], acc[kk][p]);
        }
    }

    // ---- epilogue: assocA/assocV partials (seg/sumw read-once -> nontemporal)
    const vf4a sw4 = __builtin_nontemporal_load((const vf4a*)(sumw + pix));
    const float swv[4] = {sw4.x, sw4.y, sw4.z, sw4.w};

    float accA[KT], accV[KT];
#pragma unroll
    for (int kk = 0; kk < KT; ++kk) {
        const float* sp = seg + ((long)(b * K + k0 + kk) * H + h) * W + wp;
        const vf4a s4 = __builtin_nontemporal_load((const vf4a*)sp);
        const float sv[4] = {s4.x, s4.y, s4.z, s4.w};
        float a = 0.f, v = 0.f;
#pragma unroll
        for (int p = 0; p < 4; ++p) {
            a = fmaf(acc[kk][p], sv[p], a);
            v = fmaf(swv[p], sv[p], v);
        }
        accA[kk] = a;
        accV[kk] = v;
    }

#pragma unroll
    for (int kk = 0; kk < KT; ++kk) {
        float a = accA[kk], v = accV[kk];
#pragma unroll
        for (int off = 32; off > 0; off >>= 1) {
            a += __shfl_xor(a, off);
            v += __shfl_xor(v, off);
        }
        if (lane == 0) {
            atomicAdd(&ws[b * K + k0 + kk], a);
            atomicAdd(&ws[128 + b * K + k0 + kk], v);
        }
    }
}

__global__ void ncuts_final(const float* __restrict__ ws,
                            const int* __restrict__ ncut_k,
                            float* __restrict__ out)
{
    const int t = threadIdx.x;          // 128 threads: t = b*16 + k
    const int b = t >> 4;
    const int k = t & 15;
    float r = ws[b * K + k] / ws[128 + b * K + k];
#pragma unroll
    for (int off = 1; off < 16; off <<= 1) r += __shfl_xor(r, off, 16);
    if (k == 0) out[b] = (float)(*ncut_k) - r;
}

extern "C" void kernel_launch(void* const* d_in, const int* in_sizes, int n_in,
                              void* d_out, int out_size, void* d_ws, size_t ws_size,
                              hipStream_t stream) {
    (void)in_sizes; (void)n_in; (void)out_size; (void)ws_size;
    const float* seg    = (const float*)d_in[0];
    const float* padded = (const float*)d_in[1];
    const float* weight = (const float*)d_in[2];
    const float* sumw   = (const float*)d_in[3];
    const int*   nk     = (const int*)d_in[5];
    float* ws  = (float*)d_ws;
    float* out = (float*)d_out;

    hipMemsetAsync(ws, 0, 2 * B * K * sizeof(float), stream);
    ncuts_main<<<NB, 128, 0, stream>>>(seg, padded, weight, sumw, ws);
    ncuts_final<<<1, 128, 0, stream>>>(ws, nk, out);
}

// Round 7
// 350.843 us; speedup vs baseline: 1.5043x; 1.0007x over previous
//
#include <hip/hip_runtime.h>

#define B 8
#define K 16
#define H 224
#define W 224
#define PH 232
#define PW 232
#define WIN 9
#define NP (B * H * W)            // 401408 pixels

typedef float vf4 __attribute__((ext_vector_type(4), aligned(4)));
typedef float vf4a __attribute__((ext_vector_type(4)));
typedef const __attribute__((address_space(1))) char gchar;
typedef __attribute__((address_space(3))) char lchar;

// ---------------- Kernel T: weight [pix][81] -> wT [81][pix] ----------------
// Pure-BW tiled transpose: coalesced nt float4 reads, LDS [81][132] (b128-able
// rows, stride!=0 mod 32), coalesced nt float4 writes.
__global__ __launch_bounds__(256) void ncuts_transpose(
    const float* __restrict__ wgt, float* __restrict__ wT)
{
    __shared__ float t[81][132];
    const int  pb    = blockIdx.x;            // 3136 blocks x 128 pixels
    const long gbase = (long)pb * 10368;      // 128 px * 81 floats
    const int  tid   = threadIdx.x;

#pragma unroll 1
    for (int it = 0; it < 11; ++it) {
        const int f4 = it * 256 + tid;        // float4 idx in tile, < 2592
        if (f4 < 2592) {
            vf4a v = __builtin_nontemporal_load((const vf4a*)(wgt + gbase + (long)f4 * 4));
            const int idx = f4 * 4;
#pragma unroll
            for (int tt = 0; tt < 4; ++tt) {
                const int id = idx + tt;
                const int px = id / 81;
                const int c  = id - px * 81;
                t[c][px] = ((const float*)&v)[tt];
            }
        }
    }
    __syncthreads();
#pragma unroll 1
    for (int it = 0; it < 11; ++it) {
        const int o = it * 256 + tid;         // c*32 + j, < 2592
        if (o < 2592) {
            const int c = o >> 5;
            const int j = o & 31;
            vf4a v = *(const vf4a*)&t[c][4 * j];
            __builtin_nontemporal_store(v, (vf4a*)(wT + (long)c * NP + pb * 128 + 4 * j));
        }
    }
}

// ---------------- Kernel M: main, tap-major weight ----------------
// Block: 128 thr = q(8) x kg(4) x rg(4); tile = 16 out-rows x 32 px x 4 k.
// Thread: 4 out-rows x 4 px x 1 k. Vertical reuse: one padded LDS row feeds
// up to 4 out-rows (taps m=prl-rp). Weight via wT: float4 across pixels.
__global__ __launch_bounds__(128, 3) void ncuts_mainT(
    const float* __restrict__ seg,
    const float* __restrict__ padded,
    const float* __restrict__ wT,
    const float* __restrict__ sumw,
    float* __restrict__ ws)
{
    __shared__ float lds[4][24][64];          // 24.6 KB: 4 k-planes x 24 rows
    const int tid  = threadIdx.x;
    const int lane = tid & 63;
    const int wv   = tid >> 6;

    const int bid = blockIdx.x;               // b + 8*(ks + 4*(wt + 7*ht))
    const int b   = bid & 7;                  // XCD-locality: XCD x owns b=x
    int rest      = bid >> 3;
    const int ks  = rest & 3;                 // 4 ks-partners adjacent -> same
    rest >>= 2;                               // XCD, wT tile served by L2
    const int ht  = rest / 7;
    const int wt  = rest - ht * 7;
    const int h0 = ht * 16, w0 = wt * 32, k0 = ks * 4;

    // stage padded: 4 planes x 24 rows x 40 floats (stride 64) via DMA
    {
        const int rb = lane >> 4;
        const int c  = lane & 15;
        const int cc = c < 10 ? c : 9;        // clamp fills pad, stays in-bounds
#pragma unroll
        for (int i = 0; i < 12; ++i) {
            const int j     = wv * 12 + i;    // 0..23
            const int kk    = j / 6;
            const int batch = j - kk * 6;
            const float* g = padded +
                (((long)(b * K + k0 + kk) * PH + (h0 + batch * 4 + rb)) * PW
                 + (w0 + 4 * cc));
            __builtin_amdgcn_global_load_lds((gchar*)g, (lchar*)&lds[kk][batch * 4][0], 16, 0, 0);
        }
    }
    __syncthreads();

    const int q  = tid & 7;
    const int kg = (tid >> 3) & 3;
    const int rg = tid >> 5;                  // 0..3
    const int k  = k0 + kg;
    const int hb = h0 + rg * 4;
    const long pix0 = (long)(b * H + hb) * W + w0 + 4 * q;

    float acc[4][4];
#pragma unroll
    for (int r = 0; r < 4; ++r)
#pragma unroll
        for (int p = 0; p < 4; ++p) acc[r][p] = 0.f;

#pragma unroll 1
    for (int prl = 0; prl < 12; ++prl) {      // padded row local to thread
        const float4* pr = (const float4*)&lds[kg][rg * 4 + prl][4 * q];
        const float4 a0 = pr[0], a1 = pr[1], a2 = pr[2];
        const float win[12] = {a0.x, a0.y, a0.z, a0.w,
                               a1.x, a1.y, a1.z, a1.w,
                               a2.x, a2.y, a2.z, a2.w};
        const int rlo = prl > 8 ? prl - 8 : 0;
        const int rhi = prl < 3 ? prl : 3;
#pragma unroll
        for (int rp = 0; rp < 4; ++rp) {
            if (rp < rlo || rp > rhi) continue;   // uniform branch
            const int m = prl - rp;               // tap row, 0..8
            const float* wrow = wT + (long)(m * 9) * NP + (pix0 + rp * W);
            vf4a wv4[9];
#pragma unroll
            for (int n = 0; n < 9; ++n)
                wv4[n] = *(const vf4a*)(wrow + (long)n * NP);
#pragma unroll
            for (int n = 0; n < 9; ++n)
#pragma unroll
                for (int p = 0; p < 4; ++p)
                    acc[rp][p] = fmaf(win[p + n], ((const float*)&wv4[n])[p], acc[rp][p]);
        }
    }

    // epilogue: assocA/assocV partials for this thread's 16 px x 1 k
    float aA = 0.f, aV = 0.f;
#pragma unroll
    for (int rp = 0; rp < 4; ++rp) {
        const float* sp = seg + ((long)(b * K + k) * H + hb + rp) * W + w0 + 4 * q;
        const vf4a s4  = __builtin_nontemporal_load((const vf4a*)sp);
        const vf4a sw4 = __builtin_nontemporal_load((const vf4a*)(sumw + pix0 + rp * W));
#pragma unroll
        for (int p = 0; p < 4; ++p) {
            aA = fmaf(acc[rp][p], ((const float*)&s4)[p], aA);
            aV = fmaf(((const float*)&sw4)[p], ((const float*)&s4)[p], aV);
        }
    }
    // reduce over q (bits 0-2) and rg-low (bit 5); kg lanes (bits 3-4) survive
#pragma unroll
    for (int off = 0; off < 4; ++off) {
        const int d = (off < 3) ? (1 << off) : 32;
        aA += __shfl_xor(aA, d);
        aV += __shfl_xor(aV, d);
    }
    if ((lane & 39) == 0) {                   // lanes 0,8,16,24 per wave
        atomicAdd(&ws[b * 16 + k], aA);
        atomicAdd(&ws[128 + b * 16 + k], aV);
    }
}

// ---------------- Fallback (R5 kernel, used if ws too small) ----------------
#define HT 16
#define WT 32
#define KT 4
#define ROWS (HT + 8)
#define LDSW 64
#define NWT (W / WT)
#define NB5 (B * (H / HT) * NWT * (K / KT))

__global__ __launch_bounds__(128, 3) void ncuts_fb(
    const float* __restrict__ seg, const float* __restrict__ padded,
    const float* __restrict__ weight, const float* __restrict__ sumw,
    float* __restrict__ ws)
{
    __shared__ float lds[KT][ROWS][LDSW];
    const int tid = threadIdx.x, lane = tid & 63, wv = tid >> 6;
    const int b = blockIdx.x & 7, s = blockIdx.x >> 3;
    const int kq = s & 3, tile = s >> 2;
    const int ht = tile / NWT, wt = tile - ht * NWT;
    const int k0 = kq * KT, h0 = ht * HT, w0 = wt * WT;
    {
        const int rb = lane >> 4, c = lane & 15, cc = c < 10 ? c : 9;
#pragma unroll
        for (int i = 0; i < 12; ++i) {
            const int j = wv * 12 + i, kk = j / 6, batch = j - kk * 6;
            const float* g = padded + (((long)(b * K + k0 + kk) * PH + (h0 + batch * 4 + rb)) * PW + (w0 + 4 * cc));
            __builtin_amdgcn_global_load_lds((gchar*)g, (lchar*)&lds[kk][batch * 4][0], 16, 0, 0);
        }
    }
    __syncthreads();
    const int r = tid >> 3, q = tid & 7, h = h0 + r, wp = w0 + 4 * q;
    const long pix = (long)(b * H + h) * W + wp;
    const float* wbase = weight + pix * 81;
    float acc[KT][4];
#pragma unroll
    for (int kk = 0; kk < KT; ++kk)
#pragma unroll
        for (int p = 0; p < 4; ++p) acc[kk][p] = 0.f;
#pragma unroll 1
    for (int m = 0; m < WIN; ++m) {
        float wr[4][WIN];
#pragma unroll
        for (int p = 0; p < 4; ++p) {
            const float* wpt = wbase + (long)p * 81 + m * 9;
            vf4 wa = *(const vf4*)wpt; vf4 wb = *(const vf4*)(wpt + 4);
            float wc = wpt[8];
            wr[p][0] = wa.x; wr[p][1] = wa.y; wr[p][2] = wa.z; wr[p][3] = wa.w;
            wr[p][4] = wb.x; wr[p][5] = wb.y; wr[p][6] = wb.z; wr[p][7] = wb.w;
            wr[p][8] = wc;
        }
#pragma unroll
        for (int kk = 0; kk < KT; ++kk) {
            const float4* pr = (const float4*)&lds[kk][r + m][4 * q];
            float4 a0 = pr[0], a1 = pr[1], a2 = pr[2];
            float win[12] = {a0.x, a0.y, a0.z, a0.w, a1.x, a1.y, a1.z, a1.w, a2.x, a2.y, a2.z, a2.w};
#pragma unroll
            for (int p = 0; p < 4; ++p)
#pragma unroll
                for (int n = 0; n < WIN; ++n)
                    acc[kk][p] = fmaf(win[p + n], wr[p][n], acc[kk][p]);
        }
    }
    const vf4a sw4 = __builtin_nontemporal_load((const vf4a*)(sumw + pix));
    const float swv[4] = {sw4.x, sw4.y, sw4.z, sw4.w};
#pragma unroll
    for (int kk = 0; kk < KT; ++kk) {
        const float* sp = seg + ((long)(b * K + k0 + kk) * H + h) * W + wp;
        const vf4a s4 = __builtin_nontemporal_load((const vf4a*)sp);
        float a = 0.f, v = 0.f;
#pragma unroll
        for (int p = 0; p < 4; ++p) {
            a = fmaf(acc[kk][p], ((const float*)&s4)[p], a);
            v = fmaf(swv[p], ((const float*)&s4)[p], v);
        }
#pragma unroll
        for (int off = 32; off > 0; off >>= 1) { a += __shfl_xor(a, off); v += __shfl_xor(v, off); }
        if (lane == 0) { atomicAdd(&ws[b * K + k0 + kk], a); atomicAdd(&ws[128 + b * K + k0 + kk], v); }
    }
}

__global__ void ncuts_final(const float* __restrict__ ws,
                            const int* __restrict__ ncut_k,
                            float* __restrict__ out)
{
    const int t = threadIdx.x;          // 128 threads: t = b*16 + k
    const int b = t >> 4;
    const int k = t & 15;
    float r = ws[b * K + k] / ws[128 + b * K + k];
#pragma unroll
    for (int off = 1; off < 16; off <<= 1) r += __shfl_xor(r, off, 16);
    if (k == 0) out[b] = (float)(*ncut_k) - r;
}

extern "C" void kernel_launch(void* const* d_in, const int* in_sizes, int n_in,
                              void* d_out, int out_size, void* d_ws, size_t ws_size,
                              hipStream_t stream) {
    (void)in_sizes; (void)n_in; (void)out_size;
    const float* seg    = (const float*)d_in[0];
    const float* padded = (const float*)d_in[1];
    const float* weight = (const float*)d_in[2];
    const float* sumw   = (const float*)d_in[3];
    const int*   nk     = (const int*)d_in[5];
    float* ws  = (float*)d_ws;
    float* out = (float*)d_out;

    hipMemsetAsync(ws, 0, 2 * B * K * sizeof(float), stream);

    const size_t need = 1024 + (size_t)81 * NP * 4;   // accumulators + wT
    if (ws_size >= need) {
        float* wT = ws + 256;
        ncuts_transpose<<<NP / 128, 256, 0, stream>>>(weight, wT);
        ncuts_mainT<<<8 * 4 * 7 * 14, 128, 0, stream>>>(seg, padded, wT, sumw, ws);
    } else {
        ncuts_fb<<<NB5, 128, 0, stream>>>(seg, padded, weight, sumw, ws);
    }
    ncuts_final<<<1, 128, 0, stream>>>(ws, nk, out);
}